// Round 9
// baseline (227.577 us; speedup 1.0000x reference)
//
#include <hip/hip_runtime.h>

// Sparsemax over last dim, rows of N=512 fp32.
//
// Conservative re-run of the chain-TLP experiment (r8 failed with an
// infra-anomalous signature: 538s input re-push, absmax 1e14 garbage-scale).
// This version uses ONLY round-1-proven ingredients:
//   - 256-thread blocks (all passing rounds)
//   - plain float4 loads/stores (r1; r6's asm store dropped as a variable)
//   - r1's exact DPP max/sum trees, ballot/SALU count, warm start, update
// TWO rows per wave as fully NAMED scalars, interleaved statement-by-
// statement: the sink-proof encoding of 2 concurrent solve chains per wave
// (r2/r3's array versions were provably re-serialized by the compiler:
// VGPR 32/28 cannot hold the declared state).
//
// Theory: per-row solve is a serial latency chain (~8 Michelot iterations x
// {DPP tree -> readlane -> IEEE div -> compare}); wall/row = chain /
// concurrent-chains-per-SIMD (~5 in all measured rounds). Doubling chains
// per wave should cut wall/row toward the VALU-issue floor.
//
// Numerics: each row executes EXACTLY r1's sequence (same per-lane element
// order, same trees, same update); combined break is idempotent on the
// converged row (same support -> bitwise-same tau). -> absmax 0.0.

#define ROW_N 512
#define LANES 64

typedef float f32x4 __attribute__((ext_vector_type(4)));

// One DPP step: v = v + dpp_move(v). bound_ctrl=1 -> out-of-bounds lanes read 0
// (additive identity).
#define DPP_ADD_STEP(v, ctrl, rmask)                                        \
  v += __int_as_float(__builtin_amdgcn_update_dpp(                          \
      0, __float_as_int(v), ctrl, rmask, 0xf, true))

// Full-wave (64-lane) sum; returns the total, uniform across the wave.
__device__ inline float wave_sum64(float v) {
  DPP_ADD_STEP(v, 0x111, 0xf);  // row_shr:1
  DPP_ADD_STEP(v, 0x112, 0xf);  // row_shr:2
  DPP_ADD_STEP(v, 0x114, 0xf);  // row_shr:4
  DPP_ADD_STEP(v, 0x118, 0xf);  // row_shr:8  -> lane15 of each row = row sum
  DPP_ADD_STEP(v, 0x142, 0xa);  // row_bcast:15 -> lanes 31, 63 accumulate
  DPP_ADD_STEP(v, 0x143, 0xc);  // row_bcast:31 -> lane 63 = wave total
  return __int_as_float(__builtin_amdgcn_readlane(__float_as_int(v), 63));
}

// Full-wave max: identity-old variant (invalid/masked lanes contribute v).
#define DPP_MAX_STEP(v, ctrl, rmask)                                        \
  v = fmaxf(v, __int_as_float(__builtin_amdgcn_update_dpp(                  \
             __float_as_int(v), __float_as_int(v), ctrl, rmask, 0xf, false)))

__device__ inline float wave_max64(float v) {
  DPP_MAX_STEP(v, 0x111, 0xf);
  DPP_MAX_STEP(v, 0x112, 0xf);
  DPP_MAX_STEP(v, 0x114, 0xf);
  DPP_MAX_STEP(v, 0x118, 0xf);
  DPP_MAX_STEP(v, 0x142, 0xa);
  DPP_MAX_STEP(v, 0x143, 0xc);
  return __int_as_float(__builtin_amdgcn_readlane(__float_as_int(v), 63));
}

__global__ __launch_bounds__(256) void sparsemax_kernel(
    const float* __restrict__ x, float* __restrict__ out, int nrows) {
  const int lane = threadIdx.x & 63;
  const int wave = threadIdx.x >> 6;
  const int wid = blockIdx.x * 4 + wave;
  const int rowA = wid * 2;
  if (rowA >= nrows) return;
  const bool hasB = (rowA + 1) < nrows;
  const int rowB = hasB ? rowA + 1 : rowA;  // clamp; B store gated by hasB

  const f32x4* xa = (const f32x4*)(x + (size_t)rowA * ROW_N);
  const f32x4* xb = (const f32x4*)(x + (size_t)rowB * ROW_N);
  const f32x4 a0 = xa[lane];
  const f32x4 b0 = xb[lane];
  const f32x4 a1 = xa[lane + LANES];
  const f32x4 b1 = xb[lane + LANES];

  // Named scalars — sink-proof encoding of two concurrent chains.
  float za0 = a0.x, za1 = a0.y, za2 = a0.z, za3 = a0.w;
  float za4 = a1.x, za5 = a1.y, za6 = a1.z, za7 = a1.w;
  float zb0 = b0.x, zb1 = b0.y, zb2 = b0.z, zb3 = b0.w;
  float zb4 = b1.x, zb5 = b1.y, zb6 = b1.z, zb7 = b1.w;

  // Row max (r1's exact reduction; fmax is order-exact), chains interleaved.
  float ma = za0, mb = zb0;
  ma = fmaxf(ma, za1); mb = fmaxf(mb, zb1);
  ma = fmaxf(ma, za2); mb = fmaxf(mb, zb2);
  ma = fmaxf(ma, za3); mb = fmaxf(mb, zb3);
  ma = fmaxf(ma, za4); mb = fmaxf(mb, zb4);
  ma = fmaxf(ma, za5); mb = fmaxf(mb, zb5);
  ma = fmaxf(ma, za6); mb = fmaxf(mb, zb6);
  ma = fmaxf(ma, za7); mb = fmaxf(mb, zb7);
  ma = wave_max64(ma);
  mb = wave_max64(mb);
  za0 -= ma; zb0 -= mb; za1 -= ma; zb1 -= mb;
  za2 -= ma; zb2 -= mb; za3 -= ma; zb3 -= mb;
  za4 -= ma; zb4 -= mb; za5 -= ma; zb5 -= mb;
  za6 -= ma; zb6 -= mb; za7 -= ma; zb7 -= mb;

  // Michelot, warm start tau = z_max - 1 = -1 (provable lower bound on
  // tau*). Same per-element accumulation order as r1; combined break —
  // extra iterations on a converged row are idempotent.
  float ta = -1.0f, tb = -1.0f;
  int pa = -1, pb = -1;
  for (int it = 0; it < 64; ++it) {
    float lsa = 0.0f, lsb = 0.0f;
    int ca = 0, cb = 0;
#define STEP_A(zz)                      \
  {                                     \
    const bool g = (zz) > ta;           \
    ca += (int)__popcll(__ballot(g));   \
    lsa += g ? (zz) : 0.0f;             \
  }
#define STEP_B(zz)                      \
  {                                     \
    const bool g = (zz) > tb;           \
    cb += (int)__popcll(__ballot(g));   \
    lsb += g ? (zz) : 0.0f;             \
  }
    STEP_A(za0) STEP_B(zb0)
    STEP_A(za1) STEP_B(zb1)
    STEP_A(za2) STEP_B(zb2)
    STEP_A(za3) STEP_B(zb3)
    STEP_A(za4) STEP_B(zb4)
    STEP_A(za5) STEP_B(zb5)
    STEP_A(za6) STEP_B(zb6)
    STEP_A(za7) STEP_B(zb7)
#undef STEP_A
#undef STEP_B
    lsa = wave_sum64(lsa);
    lsb = wave_sum64(lsb);
    ta = (lsa - 1.0f) / (float)ca;  // ca >= 1 always (z_max = 0 > tau)
    tb = (lsb - 1.0f) / (float)cb;
    const bool stable = (ca == pa) && (cb == pb);
    pa = ca;
    pb = cb;
    if (stable) break;  // both supports stable -> both taus fixed points
  }

  // Epilogue: plain float4 stores (r1-proven path).
  {
    f32x4* outr = (f32x4*)(out + (size_t)rowA * ROW_N);
    f32x4 o0 = {fmaxf(za0 - ta, 0.0f), fmaxf(za1 - ta, 0.0f),
                fmaxf(za2 - ta, 0.0f), fmaxf(za3 - ta, 0.0f)};
    f32x4 o1 = {fmaxf(za4 - ta, 0.0f), fmaxf(za5 - ta, 0.0f),
                fmaxf(za6 - ta, 0.0f), fmaxf(za7 - ta, 0.0f)};
    outr[lane] = o0;
    outr[lane + LANES] = o1;
  }
  if (hasB) {
    f32x4* outr = (f32x4*)(out + (size_t)rowB * ROW_N);
    f32x4 o0 = {fmaxf(zb0 - tb, 0.0f), fmaxf(zb1 - tb, 0.0f),
                fmaxf(zb2 - tb, 0.0f), fmaxf(zb3 - tb, 0.0f)};
    f32x4 o1 = {fmaxf(zb4 - tb, 0.0f), fmaxf(zb5 - tb, 0.0f),
                fmaxf(zb6 - tb, 0.0f), fmaxf(zb7 - tb, 0.0f)};
    outr[lane] = o0;
    outr[lane + LANES] = o1;
  }
}

extern "C" void kernel_launch(void* const* d_in, const int* in_sizes, int n_in,
                              void* d_out, int out_size, void* d_ws,
                              size_t ws_size, hipStream_t stream) {
  const float* x = (const float*)d_in[0];
  float* out = (float*)d_out;
  const int nrows = in_sizes[0] / ROW_N;
  const int nwaves = (nrows + 1) / 2;   // 2 rows per wave
  const int blocks = (nwaves + 3) / 4;  // 4 waves per 256-thread block
  sparsemax_kernel<<<blocks, 256, 0, stream>>>(x, out, nrows);
}